// Round 12
// baseline (16.869 us; speedup 1.0000x reference)
//
#include <hip/hip_runtime.h>
#include <math.h>

#define D    512
#define NW   4                             // waves per block; 1 item per wave
#define SWZU(u) ((u) ^ ((((u) >> 4) & 3) << 2))   // bank swizzle on b64 units

typedef __fp16 h8  __attribute__((ext_vector_type(8)));
typedef __fp16 h2  __attribute__((ext_vector_type(2)));
typedef float  f4_ __attribute__((ext_vector_type(4)));

__device__ __forceinline__ h2 cvt2(float lo, float hi) {
    return __builtin_amdgcn_cvt_pkrtz(lo, hi);
}
__device__ __forceinline__ unsigned pk(h2 v) { return __builtin_bit_cast(unsigned, v); }
__device__ __forceinline__ unsigned ab16(unsigned hi, unsigned lo) {
    return __builtin_amdgcn_alignbit(hi, lo, 16);   // (lo.hi16, hi.lo16)
}
// lane l <- lane l-2 within each 16-lane row (invalid lanes -> 0, patched after)
__device__ __forceinline__ uint2 dpp_shr2(uint2 v) {
    uint2 r;
    r.x = (unsigned)__builtin_amdgcn_mov_dpp((int)v.x, 0x112, 0xf, 0xf, true);
    r.y = (unsigned)__builtin_amdgcn_mov_dpp((int)v.y, 0x112, 0xf, 0xf, true);
    return r;
}

__global__ __launch_bounds__(256, 4) void hole_mfma_kernel(
    const float* __restrict__ ew, const float* __restrict__ eb,
    const float* __restrict__ rw, const float* __restrict__ rb,
    const int* __restrict__ xs, const int* __restrict__ ys,
    const int* __restrict__ rs, float* __restrict__ out)
{
    // per wave (uint4 slots): [0..127] bb doubled (unit-swizzled);
    // [128+66c .. 128+66c+65] a-copy shifted by c, c=0..3 (tail = wrap)
    __shared__ uint4 smem[NW][392];

    const int w    = threadIdx.x >> 6;
    const int l    = threadIdx.x & 63;
    const int mn   = l & 15;               // MFMA row m (A) == col n (B)
    const int hq   = l >> 4;               // k-group selector
    const int item = blockIdx.x * NW + w;

    const int xi = xs[item], yi = ys[item], ri = rs[item];

    // ---- rel values early (L2/L3-hot; latency hidden under gather) ----
    const float* rwrow = rw + (size_t)ri * D;
    const float* rbrow = rb + (size_t)ri * D;
    const int ridx = 64 * hq + mn;
    float rv[8];
    #pragma unroll
    for (int q = 0; q < 4; ++q) {
        rv[q]     = rwrow[ridx + 16*q]       + rbrow[ridx + 16*q];
        rv[4 + q] = rwrow[ridx + 16*q + 256] + rbrow[ridx + 16*q + 256];
    }

    // ---- gather entity rows (coalesced float4), add w+b, pack f16 ----
    const float4* xw4 = (const float4*)(ew + (size_t)xi * D);
    const float4* xb4 = (const float4*)(eb + (size_t)xi * D);
    const float4* yw4 = (const float4*)(ew + (size_t)yi * D);
    const float4* yb4 = (const float4*)(eb + (size_t)yi * D);
    float4 a0 = xw4[2*l], a1 = xw4[2*l+1], a2 = xb4[2*l], a3 = xb4[2*l+1];
    float4 b0 = yw4[2*l], b1 = yw4[2*l+1], b2 = yb4[2*l], b3 = yb4[2*l+1];

    uint4 va, vb;   // lane's f16 chunk: elements [8l .. 8l+7]
    va.x = pk(cvt2(a0.x+a2.x, a0.y+a2.y)); va.y = pk(cvt2(a0.z+a2.z, a0.w+a2.w));
    va.z = pk(cvt2(a1.x+a3.x, a1.y+a3.y)); va.w = pk(cvt2(a1.z+a3.z, a1.w+a3.w));
    vb.x = pk(cvt2(b0.x+b2.x, b0.y+b2.y)); vb.y = pk(cvt2(b0.z+b2.z, b0.w+b2.w));
    vb.z = pk(cvt2(b1.x+b3.x, b1.y+b3.y)); vb.w = pk(cvt2(b1.z+b3.z, b1.w+b3.w));

    uint4* S = smem[w];

    // ---- stage bb doubled, unit-swizzled (uint4 slot = SWZU(2l)>>1) ----
    {
        const int s0 = SWZU(2*l) >> 1;     // SWZU preserves pair adjacency
        S[s0]      = vb;                   // SWZU(u+128) = SWZU(u)+128
        S[s0 + 64] = vb;
    }
    // ---- stage 4 shifted a-copies: copy_c[i] = a[(i+c) mod 512] ----
    {
        const unsigned nx1 = (unsigned)__shfl((int)va.x, (l + 1) & 63, 64); // a[8l+8,9]
        const unsigned nx2 = (unsigned)__shfl((int)va.y, (l + 1) & 63, 64); // a[8l+10,11]
        uint4 c1, c2, c3;
        c1.x = ab16(va.y, va.x); c1.y = ab16(va.z, va.y);
        c1.z = ab16(va.w, va.z); c1.w = ab16(nx1,  va.w);
        c2.x = va.y; c2.y = va.z; c2.z = va.w; c2.w = nx1;
        c3.x = ab16(va.z, va.y); c3.y = ab16(va.w, va.z);
        c3.z = ab16(nx1,  va.w); c3.w = ab16(nx2,  nx1);
        S[128 + l]           = va;
        S[128 + 66 + l]      = c1;
        S[128 + 132 + l]     = c2;
        S[128 + 198 + l]     = c3;
        if (l < 2) {                       // wrap tails (units 128..131 of each copy)
            S[128 + 64 + l]        = va;
            S[128 + 66 + 64 + l]   = c1;
            S[128 + 132 + 64 + l]  = c2;
            S[128 + 198 + 64 + l]  = c3;
        }
    }

    // ---- MFMA main loop: 16 iters of 16x16x32, two 16x16 shift-tiles ----
    // A[m,k] = bb[512 + k - 16m - 256*tile]; B[k,n] = a[(k+n) mod 512]
    // lane: m = n = mn, k = 4hq + {0..3} + 16h + 32t
    // Recurrence: A-frag(m, t) == A-frag(m-2, t-1) -> DPP row_shr:2 pass-down;
    // only lanes m<2 re-read from LDS each iter.
    const uint2* W = (const uint2*)S;      // b64 units; bb = [0..255]
    int lu = 128 + hq - 4 * mn;            // tile0 logical unit (h0); tile1 = -64
    int ub = 256 + 132 * (mn & 3) + hq + (mn >> 2);   // a-copy b64 base

    f4_ acc0 = {0.f, 0.f, 0.f, 0.f};
    f4_ acc1 = {0.f, 0.f, 0.f, 0.f};

    uint2 p00, p01, p10, p11;
    {   // t = 0: full A read
        const int s0 = SWZU(lu), s1 = SWZU(lu + 4);
        p00 = W[s0];      p01 = W[s1];                    // tile0 h0,h1
        p10 = W[s0 - 64]; p11 = W[s1 - 64];               // tile1 h0,h1
        const uint2 q0 = W[ub], q1 = W[ub + 4];           // B h0,h1
        const h8 af0 = __builtin_bit_cast(h8, make_uint4(p00.x, p00.y, p01.x, p01.y));
        const h8 af1 = __builtin_bit_cast(h8, make_uint4(p10.x, p10.y, p11.x, p11.y));
        const h8 bf  = __builtin_bit_cast(h8, make_uint4(q0.x,  q0.y,  q1.x,  q1.y));
        acc0 = __builtin_amdgcn_mfma_f32_16x16x32_f16(af0, bf, acc0, 0, 0, 0);
        acc1 = __builtin_amdgcn_mfma_f32_16x16x32_f16(af1, bf, acc1, 0, 0, 0);
    }

    #pragma unroll
    for (int t = 1; t < 16; ++t) {
        lu += 8; ub += 8;
        // pass fragments down the m-rows in-register
        p00 = dpp_shr2(p00); p01 = dpp_shr2(p01);
        p10 = dpp_shr2(p10); p11 = dpp_shr2(p11);
        if (mn < 2) {                      // fresh rows m=0,1 (8 lanes)
            const int s0 = SWZU(lu), s1 = SWZU(lu + 4);
            p00 = W[s0];      p01 = W[s1];
            p10 = W[s0 - 64]; p11 = W[s1 - 64];
        }
        const uint2 q0 = W[ub], q1 = W[ub + 4];           // B h0,h1
        const h8 af0 = __builtin_bit_cast(h8, make_uint4(p00.x, p00.y, p01.x, p01.y));
        const h8 af1 = __builtin_bit_cast(h8, make_uint4(p10.x, p10.y, p11.x, p11.y));
        const h8 bf  = __builtin_bit_cast(h8, make_uint4(q0.x,  q0.y,  q1.x,  q1.y));
        acc0 = __builtin_amdgcn_mfma_f32_16x16x32_f16(af0, bf, acc0, 0, 0, 0);
        acc1 = __builtin_amdgcn_mfma_f32_16x16x32_f16(af1, bf, acc1, 0, 0, 0);
    }

    // ---- epilogue: rel dot, full-wave reduce, sigmoid ----
    // acc0[q] = corr_unnorm[64hq + 16q + mn]; acc1[q] = +256
    float part = acc0[0]*rv[0] + acc0[1]*rv[1] + acc0[2]*rv[2] + acc0[3]*rv[3]
               + acc1[0]*rv[4] + acc1[1]*rv[5] + acc1[2]*rv[6] + acc1[3]*rv[7];

    #pragma unroll
    for (int off = 32; off >= 1; off >>= 1) part += __shfl_down(part, off, 64);

    if (l == 0)
        out[item] = 1.0f / (1.0f + expf(-part * (1.0f / (float)D)));
}

extern "C" void kernel_launch(void* const* d_in, const int* in_sizes, int n_in,
                              void* d_out, int out_size, void* d_ws, size_t ws_size,
                              hipStream_t stream)
{
    const float* ew = (const float*)d_in[0];
    const float* eb = (const float*)d_in[1];
    const float* rw = (const float*)d_in[2];
    const float* rb = (const float*)d_in[3];
    const int*   xs = (const int*)d_in[4];
    const int*   ys = (const int*)d_in[5];
    const int*   rs = (const int*)d_in[6];
    float* out = (float*)d_out;

    const int batch = in_sizes[4];          // 4096
    dim3 grid(batch / NW), block(NW * 64);
    hole_mfma_kernel<<<grid, block, 0, stream>>>(ew, eb, rw, rb, xs, ys, rs, out);
}

// Round 13
// 13.602 us; speedup vs baseline: 1.2401x; 1.2401x over previous
//
#include <hip/hip_runtime.h>
#include <math.h>

#define D    512
#define NW   4                             // waves per block; 1 item per wave
// chunk-table swizzle: 16B chunk index, involution-free (write uses same map)
#define SWZC3(i) ((i) ^ (((i) >> 3) & 7))

typedef __fp16 h8  __attribute__((ext_vector_type(8)));
typedef __fp16 h2  __attribute__((ext_vector_type(2)));
typedef float  f4_ __attribute__((ext_vector_type(4)));

__device__ __forceinline__ h2 cvt2(float lo, float hi) {
    return __builtin_amdgcn_cvt_pkrtz(lo, hi);
}
__device__ __forceinline__ unsigned pk(h2 v) { return __builtin_bit_cast(unsigned, v); }
__device__ __forceinline__ unsigned ab16(unsigned hi, unsigned lo) {
    return __builtin_amdgcn_alignbit(hi, lo, 16);   // (lo.hi16, hi.lo16)
}

__global__ __launch_bounds__(256, 4) void hole_mfma_kernel(
    const float* __restrict__ ew, const float* __restrict__ eb,
    const float* __restrict__ rw, const float* __restrict__ rb,
    const int* __restrict__ xs, const int* __restrict__ ys,
    const int* __restrict__ rs, float* __restrict__ out)
{
    // per wave (uint4 slots):
    //  [0..255]   A-chunk table: slot SWZC3(i) = {U(i),U(i+4)}, U(j)=bb[4j..4j+3]
    //  [256..519] a-copies shifted by c=0..3 (66 slots each, incl. wrap tails)
    __shared__ uint4 smem[NW][520];

    const int w    = threadIdx.x >> 6;
    const int l    = threadIdx.x & 63;
    const int mn   = l & 15;               // MFMA row m (A) == col n (B)
    const int hq   = l >> 4;               // k-group selector
    const int item = blockIdx.x * NW + w;

    const int xi = xs[item], yi = ys[item], ri = rs[item];

    // ---- rel values early (L2/L3-hot; latency hidden under gather) ----
    const float* rwrow = rw + (size_t)ri * D;
    const float* rbrow = rb + (size_t)ri * D;
    const int ridx = 64 * hq + mn;
    float rv[8];
    #pragma unroll
    for (int q = 0; q < 4; ++q) {
        rv[q]     = rwrow[ridx + 16*q]       + rbrow[ridx + 16*q];
        rv[4 + q] = rwrow[ridx + 16*q + 256] + rbrow[ridx + 16*q + 256];
    }

    // ---- gather entity rows (coalesced float4), add w+b, pack f16 ----
    const float4* xw4 = (const float4*)(ew + (size_t)xi * D);
    const float4* xb4 = (const float4*)(eb + (size_t)xi * D);
    const float4* yw4 = (const float4*)(ew + (size_t)yi * D);
    const float4* yb4 = (const float4*)(eb + (size_t)yi * D);
    float4 a0 = xw4[2*l], a1 = xw4[2*l+1], a2 = xb4[2*l], a3 = xb4[2*l+1];
    float4 b0 = yw4[2*l], b1 = yw4[2*l+1], b2 = yb4[2*l], b3 = yb4[2*l+1];

    uint4 va, vb;   // lane's f16 chunk: elements [8l .. 8l+7]
    va.x = pk(cvt2(a0.x+a2.x, a0.y+a2.y)); va.y = pk(cvt2(a0.z+a2.z, a0.w+a2.w));
    va.z = pk(cvt2(a1.x+a3.x, a1.y+a3.y)); va.w = pk(cvt2(a1.z+a3.z, a1.w+a3.w));
    vb.x = pk(cvt2(b0.x+b2.x, b0.y+b2.y)); vb.y = pk(cvt2(b0.z+b2.z, b0.w+b2.w));
    vb.z = pk(cvt2(b1.x+b3.x, b1.y+b3.y)); vb.w = pk(cvt2(b1.z+b3.z, b1.w+b3.w));

    uint4* S = smem[w];

    // ---- stage A-chunk table: chunk(i) = {U(i), U(i+4)}, one frag per slot ----
    // lane l holds U(2l)=vb.xy, U(2l+1)=vb.zw; U(2l+4),U(2l+5) from lane l+2
    {
        const int l2 = (l + 2) & 63;       // wrap: doubled-bb semantics
        uint4 nb;
        nb.x = (unsigned)__shfl((int)vb.x, l2, 64);
        nb.y = (unsigned)__shfl((int)vb.y, l2, 64);
        nb.z = (unsigned)__shfl((int)vb.z, l2, 64);
        nb.w = (unsigned)__shfl((int)vb.w, l2, 64);
        const int s0 = SWZC3(2*l), s1 = SWZC3(2*l + 1);
        const uint4 ch0 = make_uint4(vb.x, vb.y, nb.x, nb.y);   // chunk 2l
        const uint4 ch1 = make_uint4(vb.z, vb.w, nb.z, nb.w);   // chunk 2l+1
        S[s0]       = ch0;                 // SWZC3(i+128) == SWZC3(i)+128
        S[s1]       = ch1;
        S[s0 + 128] = ch0;                 // chunk(i+128) == chunk(i)
        S[s1 + 128] = ch1;
    }
    // ---- stage 4 shifted a-copies: copy_c[i] = a[(i+c) mod 512] ----
    {
        const unsigned nx1 = (unsigned)__shfl((int)va.x, (l + 1) & 63, 64); // a[8l+8,9]
        const unsigned nx2 = (unsigned)__shfl((int)va.y, (l + 1) & 63, 64); // a[8l+10,11]
        uint4 c1, c2, c3;
        c1.x = ab16(va.y, va.x); c1.y = ab16(va.z, va.y);
        c1.z = ab16(va.w, va.z); c1.w = ab16(nx1,  va.w);
        c2.x = va.y; c2.y = va.z; c2.z = va.w; c2.w = nx1;
        c3.x = ab16(va.z, va.y); c3.y = ab16(va.w, va.z);
        c3.z = ab16(nx1,  va.w); c3.w = ab16(nx2,  nx1);
        S[256 + l]           = va;
        S[256 + 66 + l]      = c1;
        S[256 + 132 + l]     = c2;
        S[256 + 198 + l]     = c3;
        if (l < 2) {                       // wrap tails
            S[256 + 64 + l]        = va;
            S[256 + 66 + 64 + l]   = c1;
            S[256 + 132 + 64 + l]  = c2;
            S[256 + 198 + 64 + l]  = c3;
        }
    }

    // ---- MFMA main loop: 16 iters of 16x16x32, two 16x16 shift-tiles ----
    // A-frag(m,t,tile) = chunk(128 + hq + 8t - 4m - 64*tile)  -> ONE b128 read
    // B[k,n] = a[(k+n) mod 512] via shifted copies            -> two b64 reads
    const uint2* W = (const uint2*)S;      // b64 units; a-copies start at unit 512
    int ca = 128 + hq - 4 * mn;            // tile0 chunk idx; tile1 = ca - 64
    int ub = 512 + 132 * (mn & 3) + hq + (mn >> 2);   // a-copy b64 base

    f4_ acc0 = {0.f, 0.f, 0.f, 0.f};
    f4_ acc1 = {0.f, 0.f, 0.f, 0.f};

    #pragma unroll
    for (int t = 0; t < 16; ++t) {
        const uint4 A0 = S[SWZC3(ca)];                    // tile0 frag (b128)
        const uint4 A1 = S[SWZC3(ca - 64)];               // tile1 frag (b128)
        const uint2 q0 = W[ub], q1 = W[ub + 4];           // B h0,h1

        const h8 af0 = __builtin_bit_cast(h8, A0);
        const h8 af1 = __builtin_bit_cast(h8, A1);
        const h8 bf  = __builtin_bit_cast(h8, make_uint4(q0.x, q0.y, q1.x, q1.y));

        acc0 = __builtin_amdgcn_mfma_f32_16x16x32_f16(af0, bf, acc0, 0, 0, 0);
        acc1 = __builtin_amdgcn_mfma_f32_16x16x32_f16(af1, bf, acc1, 0, 0, 0);

        ca += 8; ub += 8;
    }

    // ---- epilogue: rel dot, full-wave reduce, sigmoid ----
    // acc0[q] = corr_unnorm[64hq + 16q + mn]; acc1[q] = +256
    float part = acc0[0]*rv[0] + acc0[1]*rv[1] + acc0[2]*rv[2] + acc0[3]*rv[3]
               + acc1[0]*rv[4] + acc1[1]*rv[5] + acc1[2]*rv[6] + acc1[3]*rv[7];

    #pragma unroll
    for (int off = 32; off >= 1; off >>= 1) part += __shfl_down(part, off, 64);

    if (l == 0)
        out[item] = 1.0f / (1.0f + expf(-part * (1.0f / (float)D)));
}

extern "C" void kernel_launch(void* const* d_in, const int* in_sizes, int n_in,
                              void* d_out, int out_size, void* d_ws, size_t ws_size,
                              hipStream_t stream)
{
    const float* ew = (const float*)d_in[0];
    const float* eb = (const float*)d_in[1];
    const float* rw = (const float*)d_in[2];
    const float* rb = (const float*)d_in[3];
    const int*   xs = (const int*)d_in[4];
    const int*   ys = (const int*)d_in[5];
    const int*   rs = (const int*)d_in[6];
    float* out = (float*)d_out;

    const int batch = in_sizes[4];          // 4096
    dim3 grid(batch / NW), block(NW * 64);
    hole_mfma_kernel<<<grid, block, 0, stream>>>(ew, eb, rw, rb, xs, ys, rs, out);
}